// Round 7
// baseline (274.661 us; speedup 1.0000x reference)
//
#include <hip/hip_runtime.h>
#include <math.h>
#include <stdint.h>

#define NLEV 16
#define TSIZE (1u << 19)
#define NB 4096
#define NS 48
#define NPTS (NB * NS)

typedef __attribute__((ext_vector_type(8))) short short8;
typedef __attribute__((ext_vector_type(4))) float f32x4;

struct Scales { float s[NLEV]; };

__device__ __forceinline__ uint32_t hash3(uint32_t x, uint32_t y, uint32_t z) {
    return (x ^ (y * 2654435761u) ^ (z * 805459861u)) & (TSIZE - 1u);
}

__device__ __forceinline__ float sigmoidf(float v) {
    return 1.0f / (1.0f + expf(-v));
}

// fp32 -> bf16 (round to nearest even), raw ushort bits
__device__ __forceinline__ ushort f2b(float f) {
    union { float f; uint32_t u; } v; v.f = f;
    uint32_t r = (v.u + 0x7FFFu + ((v.u >> 16) & 1u)) >> 16;
    return (ushort)r;
}

#define MFMA16(a, b, c) __builtin_amdgcn_mfma_f32_16x16x32_bf16((a), (b), (c), 0, 0, 0)

// Fragment bank: 20 B-fragments, each 64 lanes x 8 bf16 (1 KB), lane-ordered
// so a wave loads one fragment with a single coalesced dwordx4.
//   f0..3  : W1^T  n-tile 0..3          (L1, k=quad*8+j)
//   f4..5  : W2^T  k-half 0..1          (L2)
//   f6..9  : H1^T  n-tile 0..3          (L3)
//   f10..17: H2^T  (nt,kk) = (f-10)>>1, (f-10)&1   (L4)
//   f18..19: H3^T  k-half 0..1 (cols>=3 zero)      (L5)
__global__ __launch_bounds__(256) void prep_kernel(
    const float* __restrict__ w1, const float* __restrict__ w2,
    const float* __restrict__ h1, const float* __restrict__ h2,
    const float* __restrict__ h3,
    ushort* __restrict__ bank)
{
    for (int idx = threadIdx.x; idx < 20 * 512; idx += 256) {
        const int f    = idx >> 9;
        const int r    = idx & 511;
        const int lane = r >> 3;
        const int j    = r & 7;
        const int l15  = lane & 15;
        const int quad = lane >> 4;
        const int k8   = quad * 8 + j;   // 0..31
        float val;
        if (f < 4) {
            val = w1[k8 * 64 + f * 16 + l15];
        } else if (f < 6) {
            val = w2[((f - 4) * 32 + k8) * 16 + l15];
        } else if (f < 10) {
            val = h1[k8 * 64 + (f - 6) * 16 + l15];
        } else if (f < 18) {
            const int t = f - 10, nt = t >> 1, kk = t & 1;
            val = h2[(kk * 32 + k8) * 64 + nt * 16 + l15];
        } else {
            val = (l15 < 3) ? h3[((f - 18) * 32 + k8) * 3 + l15] : 0.0f;
        }
        bank[idx] = f2b(val);
    }
}

// Fused encode+MLP. One block = 64 points, 4 waves.
// Phase 0: 64 threads do camera transform -> sQ, SH16 -> sHIN.
// Phase 1: 1024 (point,level) gather tasks, 4/thread; wave wv handles levels
//          {wv, 4+wv, 8+wv, 12+wv} (wave-uniform level => scalar table base).
// Phase 2: 5-layer MFMA chain with an explicit __syncthreads() between every
//          layer. RACE LESSON (round 6): HW executes a wave's DS ops in
//          order, but the COMPILER may reorder ds_read before a prior
//          ds_write when per-thread alias analysis sees disjoint addresses —
//          cross-lane data flow through LDS is invisible to it. Never rely
//          on barrier-free intra-wave LDS chaining.
// Layouts (verified m89/m120):
//   A: [m=lane&15][k=quad*8+j]  B: [n=lane&15][k=quad*8+j]
//   C/D: col=lane&15, row=quad*4+reg
__global__ __launch_bounds__(256) void fused_kernel(
    const float* __restrict__ positions,
    const float* __restrict__ normals,
    const float* __restrict__ c2w,
    const float* __restrict__ table,
    const ushort* __restrict__ bank,
    const float* __restrict__ b1, const float* __restrict__ b2,
    const float* __restrict__ hb1, const float* __restrict__ hb2,
    const float* __restrict__ hb3,
    float* __restrict__ rgb_out,
    Scales sc)
{
    __shared__ float4 sQ[64];
    __shared__ ushort sX[64 * 40];    // L1 input  (32 feats + pad)
    __shared__ ushort sA1[64 * 72];   // L1 output (64); reused as V (L4 out)
    __shared__ ushort sHIN[64 * 40];  // [SH16 | geo16] (+ pad)
    __shared__ ushort sU[64 * 72];    // L3 output (64)

    const int tid = threadIdx.x;
    const int p0  = blockIdx.x * 64;

    // ---- phase 0: transform + SH16 (one thread per point) ----
    if (tid < 64) {
        const int p = p0 + tid;
        const int b = p / NS;
        const float* M = c2w + b * 12;
        const float px = positions[3 * p + 0];
        const float py = positions[3 * p + 1];
        const float pz = positions[3 * p + 2];
        const float dx = px - M[3], dy = py - M[7], dz = pz - M[11];
        float qx = M[0] * dx + M[4] * dy + M[8] * dz;
        float qy = M[1] * dx + M[5] * dy + M[9] * dz;
        float qz = M[2] * dx + M[6] * dy + M[10] * dz;
        qx = (qx + 1.0f) * 0.5f;
        qy = (qy + 1.0f) * 0.5f;
        qz = (qz + 1.0f) * 0.5f;
        const bool sel = (qx > 0.0f) && (qx < 1.0f) &&
                         (qy > 0.0f) && (qy < 1.0f) &&
                         (qz > 0.0f) && (qz < 1.0f);
        if (!sel) { qx = 0.0f; qy = 0.0f; qz = 0.0f; }
        sQ[tid] = make_float4(qx, qy, qz, 0.0f);

        const float n0 = normals[3 * b + 0];
        const float n1 = normals[3 * b + 1];
        const float n2 = normals[3 * b + 2];
        float x = M[0] * n0 + M[4] * n1 + M[8] * n2;
        float y = M[1] * n0 + M[5] * n1 + M[9] * n2;
        float z = M[2] * n0 + M[6] * n1 + M[10] * n2;
        x = (x + 1.0f) * 0.5f;
        y = (y + 1.0f) * 0.5f;
        z = (z + 1.0f) * 0.5f;
        const float xx = x * x, yy = y * y, zz = z * z;
        float sh[16];
        sh[0]  = 0.28209479177387814f;
        sh[1]  = -0.48860251190291987f * y;
        sh[2]  = 0.48860251190291987f * z;
        sh[3]  = -0.48860251190291987f * x;
        sh[4]  = 1.0925484305920792f * x * y;
        sh[5]  = -1.0925484305920792f * y * z;
        sh[6]  = 0.94617469575756f * zz - 0.31539156525252f;
        sh[7]  = -1.0925484305920792f * x * z;
        sh[8]  = 0.5462742152960396f * (xx - yy);
        sh[9]  = 0.5900435899266435f * y * (3.0f * xx - yy);
        sh[10] = 2.890611442640554f * x * y * z;
        sh[11] = 0.4570457994644657f * y * (5.0f * zz - 1.0f);
        sh[12] = 0.37317633259011546f * z * (5.0f * zz - 3.0f);
        sh[13] = 0.4570457994644657f * x * (5.0f * zz - 1.0f);
        sh[14] = 1.445305721320277f * z * (xx - yy);
        sh[15] = 0.5900435899266435f * x * (xx - 3.0f * yy);
#pragma unroll
        for (int i = 0; i < 16; ++i) sHIN[tid * 40 + i] = f2b(sh[i]);
    }
    __syncthreads();

    // ---- phase 1: hash-grid gathers, 4 (point,level) tasks per thread ----
    {
        const int pt = tid & 63;       // point-in-block
        const int wv4 = tid >> 6;      // wave id
        const float4 q = sQ[pt];
#pragma unroll
        for (int i = 0; i < 4; ++i) {
            const int l = i * 4 + wv4;                 // wave-uniform level
            const float s = sc.s[l];
            const float sx = q.x * s, sy = q.y * s, sz = q.z * s;
            const float fx = floorf(sx), fy = floorf(sy), fz = floorf(sz);
            const float cx = ceilf(sx),  cy = ceilf(sy),  cz = ceilf(sz);
            const float ox = sx - fx, oy = sy - fy, oz = sz - fz;
            const uint32_t fxi = (uint32_t)fx, fyi = (uint32_t)fy, fzi = (uint32_t)fz;
            const uint32_t cxi = (uint32_t)cx, cyi = (uint32_t)cy, czi = (uint32_t)cz;

            const float2* tab2 = (const float2*)table + (uint32_t)l * TSIZE;
            const float2 f0 = tab2[hash3(cxi, cyi, czi)];
            const float2 f1 = tab2[hash3(cxi, fyi, czi)];
            const float2 f2 = tab2[hash3(fxi, fyi, czi)];
            const float2 f3 = tab2[hash3(fxi, cyi, czi)];
            const float2 f4 = tab2[hash3(cxi, cyi, fzi)];
            const float2 f5 = tab2[hash3(cxi, fyi, fzi)];
            const float2 f6 = tab2[hash3(fxi, fyi, fzi)];
            const float2 f7 = tab2[hash3(fxi, cyi, fzi)];

            const float omx = 1.0f - ox, omy = 1.0f - oy, omz = 1.0f - oz;
            float f03x = f0.x * ox + f3.x * omx, f03y = f0.y * ox + f3.y * omx;
            float f12x = f1.x * ox + f2.x * omx, f12y = f1.y * ox + f2.y * omx;
            float f56x = f5.x * ox + f6.x * omx, f56y = f5.y * ox + f6.y * omx;
            float f47x = f4.x * ox + f7.x * omx, f47y = f4.y * ox + f7.y * omx;
            float ax = f03x * oy + f12x * omy, ay = f03y * oy + f12y * omy;
            float bx = f47x * oy + f56x * omy, by = f47y * oy + f56y * omy;
            const float ex = ax * oz + bx * omz;
            const float ey = ay * oz + by * omz;
            *(uint32_t*)&sX[pt * 40 + 2 * l] =
                ((uint32_t)f2b(ey) << 16) | (uint32_t)f2b(ex);
        }
    }

    const int lane = tid & 63;
    const int wv   = tid >> 6;
    const int l15  = lane & 15;
    const int quad = lane >> 4;
    float b1v[4], hb1v[4], hb2v[4];
#pragma unroll
    for (int nt = 0; nt < 4; ++nt) {
        b1v[nt]  = b1[nt * 16 + l15];
        hb1v[nt] = hb1[nt * 16 + l15];
        hb2v[nt] = hb2[nt * 16 + l15];
    }
    const float b2v  = b2[l15];
    const float hb3v = (l15 < 3) ? hb3[l15] : 0.0f;

    const ushort* fb = bank + lane * 8;  // this lane's slot in each fragment
#define FRAG(f) (*(const short8*)(fb + (f) * 512))

    __syncthreads();

    const int arow  = wv * 16 + l15;        // A-operand row (point in block)
    const int crow0 = wv * 16 + quad * 4;   // C-layout base row
    const f32x4 zero = {0.0f, 0.0f, 0.0f, 0.0f};

    // ---- L1: X(32) @ W1 -> 64, +b1, relu -> sA1 ----
    {
        const short8 a = *(const short8*)&sX[arow * 40 + quad * 8];
        f32x4 c[4];
#pragma unroll
        for (int nt = 0; nt < 4; ++nt) c[nt] = MFMA16(a, FRAG(nt), zero);
#pragma unroll
        for (int nt = 0; nt < 4; ++nt)
#pragma unroll
            for (int r = 0; r < 4; ++r) {
                const float v = fmaxf(c[nt][r] + b1v[nt], 0.0f);
                sA1[(crow0 + r) * 72 + nt * 16 + l15] = f2b(v);
            }
    }
    __syncthreads();

    // ---- L2: A1(64) @ W2 -> 16 geo, +b2, relu -> sHIN[:,16:32] ----
    {
        const short8 a0 = *(const short8*)&sA1[arow * 72 + quad * 8];
        const short8 a1 = *(const short8*)&sA1[arow * 72 + 32 + quad * 8];
        f32x4 c = MFMA16(a0, FRAG(4), zero);
        c = MFMA16(a1, FRAG(5), c);
#pragma unroll
        for (int r = 0; r < 4; ++r) {
            const float v = fmaxf(c[r] + b2v, 0.0f);
            sHIN[(crow0 + r) * 40 + 16 + l15] = f2b(v);
        }
    }
    __syncthreads();

    // ---- L3: HIN(32) @ H1 -> 64, +hb1, relu -> sU ----
    {
        const short8 a = *(const short8*)&sHIN[arow * 40 + quad * 8];
        f32x4 c[4];
#pragma unroll
        for (int nt = 0; nt < 4; ++nt) c[nt] = MFMA16(a, FRAG(6 + nt), zero);
#pragma unroll
        for (int nt = 0; nt < 4; ++nt)
#pragma unroll
            for (int r = 0; r < 4; ++r) {
                const float v = fmaxf(c[nt][r] + hb1v[nt], 0.0f);
                sU[(crow0 + r) * 72 + nt * 16 + l15] = f2b(v);
            }
    }
    __syncthreads();

    // ---- L4: U(64) @ H2 -> 64, +hb2, relu -> sA1 (reused as V) ----
    {
        const short8 a0 = *(const short8*)&sU[arow * 72 + quad * 8];
        const short8 a1 = *(const short8*)&sU[arow * 72 + 32 + quad * 8];
        f32x4 c[4];
#pragma unroll
        for (int nt = 0; nt < 4; ++nt) {
            f32x4 t = MFMA16(a0, FRAG(10 + nt * 2), zero);
            c[nt] = MFMA16(a1, FRAG(11 + nt * 2), t);
        }
        __syncthreads();  // WAR: sA1 still being read above by other waves? no —
                          // intra-wave rows, but keep write after barrier for
                          // uniform discipline (all waves reach here).
#pragma unroll
        for (int nt = 0; nt < 4; ++nt)
#pragma unroll
            for (int r = 0; r < 4; ++r) {
                const float v = fmaxf(c[nt][r] + hb2v[nt], 0.0f);
                sA1[(crow0 + r) * 72 + nt * 16 + l15] = f2b(v);
            }
    }
    __syncthreads();

    // ---- L5: V(64) @ H3 -> 3, +hb3, sigmoid -> rgb ----
    {
        const short8 a0 = *(const short8*)&sA1[arow * 72 + quad * 8];
        const short8 a1 = *(const short8*)&sA1[arow * 72 + 32 + quad * 8];
        f32x4 c = MFMA16(a0, FRAG(18), zero);
        c = MFMA16(a1, FRAG(19), c);
        if (l15 < 3) {
#pragma unroll
            for (int r = 0; r < 4; ++r) {
                rgb_out[3 * (p0 + crow0 + r) + l15] = sigmoidf(c[r] + hb3v);
            }
        }
    }
#undef FRAG
}

// k3: one 64-thread block per batch. Softmax over S=48, weighted rgb sum.
__global__ __launch_bounds__(64) void reduce_kernel(
    const float* __restrict__ densities,
    const float* __restrict__ rgb,
    float* __restrict__ out)
{
    const int b = blockIdx.x;
    const int t = threadIdx.x;
    const bool valid = t < NS;

    float d = valid ? densities[b * NS + t] : -INFINITY;
    float m = d;
#pragma unroll
    for (int off = 32; off > 0; off >>= 1) m = fmaxf(m, __shfl_xor(m, off));
    float e = valid ? expf(d - m) : 0.0f;
    float sum = e;
#pragma unroll
    for (int off = 32; off > 0; off >>= 1) sum += __shfl_xor(sum, off);
    const float w = e / sum;

    float r0 = 0.0f, r1 = 0.0f, r2 = 0.0f;
    if (valid) {
        const int base = (b * NS + t) * 3;
        r0 = w * rgb[base + 0];
        r1 = w * rgb[base + 1];
        r2 = w * rgb[base + 2];
    }
#pragma unroll
    for (int off = 32; off > 0; off >>= 1) {
        r0 += __shfl_xor(r0, off);
        r1 += __shfl_xor(r1, off);
        r2 += __shfl_xor(r2, off);
    }
    if (t == 0) {
        out[3 * b + 0] = r0;
        out[3 * b + 1] = r1;
        out[3 * b + 2] = r2;
    }
}

extern "C" void kernel_launch(void* const* d_in, const int* in_sizes, int n_in,
                              void* d_out, int out_size, void* d_ws, size_t ws_size,
                              hipStream_t stream) {
    const float* positions = (const float*)d_in[0];
    const float* densities = (const float*)d_in[1];
    const float* normals   = (const float*)d_in[2];
    const float* c2w       = (const float*)d_in[3];
    const float* table     = (const float*)d_in[4];
    const float* w1  = (const float*)d_in[5];
    const float* b1  = (const float*)d_in[6];
    const float* w2  = (const float*)d_in[7];
    const float* b2  = (const float*)d_in[8];
    const float* h1  = (const float*)d_in[9];
    const float* hb1 = (const float*)d_in[10];
    const float* h2  = (const float*)d_in[11];
    const float* hb2 = (const float*)d_in[12];
    const float* h3  = (const float*)d_in[13];
    const float* hb3 = (const float*)d_in[14];
    float* out = (float*)d_out;

    // ws layout: bank (20KB) | rgb (NPTS*3 f32)
    ushort* bank   = (ushort*)d_ws;
    float*  rgb_ws = (float*)((char*)d_ws + 20 * 1024);

    Scales sc;
    const double growth = exp((log(2048.0) - log(16.0)) / 15.0);
    for (int i = 0; i < NLEV; ++i)
        sc.s[i] = (float)floor(16.0 * pow(growth, (double)i));

    prep_kernel<<<1, 256, 0, stream>>>(w1, w2, h1, h2, h3, bank);
    fused_kernel<<<NPTS / 64, 256, 0, stream>>>(
        positions, normals, c2w, table, bank,
        b1, b2, hb1, hb2, hb3, rgb_ws, sc);
    reduce_kernel<<<NB, 64, 0, stream>>>(densities, rgb_ws, out);
}

// Round 8
// 238.205 us; speedup vs baseline: 1.1530x; 1.1530x over previous
//
#include <hip/hip_runtime.h>
#include <math.h>
#include <stdint.h>

#define NLEV 16
#define TSIZE (1u << 19)
#define NB 4096
#define NS 48
#define NPTS (NB * NS)

typedef __attribute__((ext_vector_type(8))) short short8;
typedef __attribute__((ext_vector_type(4))) float f32x4;

struct Scales { float s[NLEV]; };

__device__ __forceinline__ uint32_t hash3(uint32_t x, uint32_t y, uint32_t z) {
    return (x ^ (y * 2654435761u) ^ (z * 805459861u)) & (TSIZE - 1u);
}

__device__ __forceinline__ float sigmoidf(float v) {
    return 1.0f / (1.0f + expf(-v));
}

// fp32 -> bf16 (round to nearest even), raw ushort bits
__device__ __forceinline__ ushort f2b(float f) {
    union { float f; uint32_t u; } v; v.f = f;
    uint32_t r = (v.u + 0x7FFFu + ((v.u >> 16) & 1u)) >> 16;
    return (ushort)r;
}

__device__ __forceinline__ float blo(uint32_t v) {
    union { uint32_t u; float f; } t; t.u = v << 16; return t.f;
}
__device__ __forceinline__ float bhi(uint32_t v) {
    union { uint32_t u; float f; } t; t.u = v & 0xFFFF0000u; return t.f;
}

#define MFMA16(a, b, c) __builtin_amdgcn_mfma_f32_16x16x32_bf16((a), (b), (c), 0, 0, 0)

// prep: (block 0) build the 20-fragment weight bank; (all blocks) optionally
// convert the 64 MB fp32 table to packed-bf16 (u32 = hi:y | lo:x), 32 MB.
// Fragment bank layout (see round 5): f0..3 W1^T | f4..5 W2^T | f6..9 H1^T |
// f10..17 H2^T | f18..19 H3^T(cols>=3 zero); each frag = 64 lanes x 8 bf16.
__global__ __launch_bounds__(256) void prep_kernel(
    const float* __restrict__ w1, const float* __restrict__ w2,
    const float* __restrict__ h1, const float* __restrict__ h2,
    const float* __restrict__ h3,
    const float* __restrict__ table,
    ushort* __restrict__ bank,
    uint32_t* __restrict__ tb16)   // may be null (fallback path)
{
    if (blockIdx.x == 0) {
        for (int idx = threadIdx.x; idx < 20 * 512; idx += 256) {
            const int f    = idx >> 9;
            const int r    = idx & 511;
            const int lane = r >> 3;
            const int j    = r & 7;
            const int l15  = lane & 15;
            const int quad = lane >> 4;
            const int k8   = quad * 8 + j;   // 0..31
            float val;
            if (f < 4) {
                val = w1[k8 * 64 + f * 16 + l15];
            } else if (f < 6) {
                val = w2[((f - 4) * 32 + k8) * 16 + l15];
            } else if (f < 10) {
                val = h1[k8 * 64 + (f - 6) * 16 + l15];
            } else if (f < 18) {
                const int t = f - 10, nt = t >> 1, kk = t & 1;
                val = h2[(kk * 32 + k8) * 64 + nt * 16 + l15];
            } else {
                val = (l15 < 3) ? h3[((f - 18) * 32 + k8) * 3 + l15] : 0.0f;
            }
            bank[idx] = f2b(val);
        }
    }
    if (tb16) {
        const float2* t2 = (const float2*)table;
        const int n = NLEV * TSIZE;
        for (int i = blockIdx.x * blockDim.x + threadIdx.x; i < n;
             i += gridDim.x * blockDim.x) {
            const float2 e = t2[i];
            tb16[i] = ((uint32_t)f2b(e.y) << 16) | (uint32_t)f2b(e.x);
        }
    }
}

// Shared encode body (transform folded in). 1-D grid, level = bid & 15 so
// (with the bid%8 XCD round-robin heuristic) XCD k only touches level slices
// {k, k+8} — a 2-slice L2 working set instead of all 16.
#define ENCODE_PROLOG()                                                       \
    const int bid = blockIdx.x;                                               \
    const int l   = bid & 15;                /* wave-uniform level */         \
    const int p   = (bid >> 4) * 256 + threadIdx.x;                           \
    const int b   = p / NS;                                                   \
    const float* M = c2w + b * 12;                                            \
    const float px = positions[3 * p + 0];                                    \
    const float py = positions[3 * p + 1];                                    \
    const float pz = positions[3 * p + 2];                                    \
    const float dx = px - M[3], dy = py - M[7], dz = pz - M[11];              \
    float qx = M[0] * dx + M[4] * dy + M[8] * dz;                             \
    float qy = M[1] * dx + M[5] * dy + M[9] * dz;                             \
    float qz = M[2] * dx + M[6] * dy + M[10] * dz;                            \
    qx = (qx + 1.0f) * 0.5f;                                                  \
    qy = (qy + 1.0f) * 0.5f;                                                  \
    qz = (qz + 1.0f) * 0.5f;                                                  \
    const bool sel = (qx > 0.0f) && (qx < 1.0f) &&                            \
                     (qy > 0.0f) && (qy < 1.0f) &&                            \
                     (qz > 0.0f) && (qz < 1.0f);                              \
    if (!sel) { qx = 0.0f; qy = 0.0f; qz = 0.0f; }                            \
    const float s = sc.s[l];                                                  \
    const float sx = qx * s, sy = qy * s, sz = qz * s;                        \
    const float fx = floorf(sx), fy = floorf(sy), fz = floorf(sz);            \
    const float cx = ceilf(sx),  cy = ceilf(sy),  cz = ceilf(sz);             \
    const float ox = sx - fx, oy = sy - fy, oz = sz - fz;                     \
    const uint32_t fxi = (uint32_t)fx, fyi = (uint32_t)fy, fzi = (uint32_t)fz;\
    const uint32_t cxi = (uint32_t)cx, cyi = (uint32_t)cy, czi = (uint32_t)cz;

#define ENCODE_EPILOG()                                                       \
    const float omx = 1.0f - ox, omy = 1.0f - oy, omz = 1.0f - oz;            \
    float f03x = f0x * ox + f3x * omx, f03y = f0y * ox + f3y * omx;           \
    float f12x = f1x * ox + f2x * omx, f12y = f1y * ox + f2y * omx;           \
    float f56x = f5x * ox + f6x * omx, f56y = f5y * ox + f6y * omx;           \
    float f47x = f4x * ox + f7x * omx, f47y = f4y * ox + f7y * omx;           \
    float ax = f03x * oy + f12x * omy, ay = f03y * oy + f12y * omy;           \
    float bx = f47x * oy + f56x * omy, by = f47y * oy + f56y * omy;           \
    const float ex = ax * oz + bx * omz;                                      \
    const float ey = ay * oz + by * omz;                                      \
    enc_ws[l * NPTS + p] = ((uint32_t)f2b(ey) << 16) | (uint32_t)f2b(ex);

// encode, bf16-packed table path (4 B per corner gather)
__global__ __launch_bounds__(256) void encode_kernel_b16(
    const float* __restrict__ positions,
    const float* __restrict__ c2w,
    const uint32_t* __restrict__ tb16,
    uint32_t* __restrict__ enc_ws,
    Scales sc)
{
    ENCODE_PROLOG();
    const uint32_t* tab = tb16 + (uint32_t)l * TSIZE;
    const uint32_t e0 = tab[hash3(cxi, cyi, czi)];
    const uint32_t e1 = tab[hash3(cxi, fyi, czi)];
    const uint32_t e2 = tab[hash3(fxi, fyi, czi)];
    const uint32_t e3 = tab[hash3(fxi, cyi, czi)];
    const uint32_t e4 = tab[hash3(cxi, cyi, fzi)];
    const uint32_t e5 = tab[hash3(cxi, fyi, fzi)];
    const uint32_t e6 = tab[hash3(fxi, fyi, fzi)];
    const uint32_t e7 = tab[hash3(fxi, cyi, fzi)];
    const float f0x = blo(e0), f0y = bhi(e0);
    const float f1x = blo(e1), f1y = bhi(e1);
    const float f2x = blo(e2), f2y = bhi(e2);
    const float f3x = blo(e3), f3y = bhi(e3);
    const float f4x = blo(e4), f4y = bhi(e4);
    const float f5x = blo(e5), f5y = bhi(e5);
    const float f6x = blo(e6), f6y = bhi(e6);
    const float f7x = blo(e7), f7y = bhi(e7);
    ENCODE_EPILOG();
}

// encode, fp32 table path (fallback when ws too small for tb16)
__global__ __launch_bounds__(256) void encode_kernel_f32(
    const float* __restrict__ positions,
    const float* __restrict__ c2w,
    const float* __restrict__ table,
    uint32_t* __restrict__ enc_ws,
    Scales sc)
{
    ENCODE_PROLOG();
    const float2* tab = (const float2*)table + (uint32_t)l * TSIZE;
    const float2 g0 = tab[hash3(cxi, cyi, czi)];
    const float2 g1 = tab[hash3(cxi, fyi, czi)];
    const float2 g2 = tab[hash3(fxi, fyi, czi)];
    const float2 g3 = tab[hash3(fxi, cyi, czi)];
    const float2 g4 = tab[hash3(cxi, cyi, fzi)];
    const float2 g5 = tab[hash3(cxi, fyi, fzi)];
    const float2 g6 = tab[hash3(fxi, fyi, fzi)];
    const float2 g7 = tab[hash3(fxi, cyi, fzi)];
    const float f0x = g0.x, f0y = g0.y;
    const float f1x = g1.x, f1y = g1.y;
    const float f2x = g2.x, f2y = g2.y;
    const float f3x = g3.x, f3y = g3.y;
    const float f4x = g4.x, f4y = g4.y;
    const float f5x = g5.x, f5y = g5.y;
    const float f6x = g6.x, f6y = g6.y;
    const float f7x = g7.x, f7y = g7.y;
    ENCODE_EPILOG();
}

// MFMA MLP (round-5 structure + inter-layer barriers — round-6 race lesson:
// the compiler may reorder ds_read before prior ds_write across lanes; never
// chain LDS layers without __syncthreads).
// Layouts (verified m89/m120):
//   A: [m=lane&15][k=quad*8+j]  B: [n=lane&15][k=quad*8+j]
//   C/D: col=lane&15, row=quad*4+reg
__global__ __launch_bounds__(256) void mfma_mlp_kernel(
    const uint32_t* __restrict__ enc_ws,
    const float* __restrict__ normals,
    const float* __restrict__ c2w,
    const ushort* __restrict__ bank,
    const float* __restrict__ b1, const float* __restrict__ b2,
    const float* __restrict__ hb1, const float* __restrict__ hb2,
    const float* __restrict__ hb3,
    float* __restrict__ rgb_out)
{
    __shared__ ushort sX[64 * 40];    // L1 input  (32 feats + pad)
    __shared__ ushort sA1[64 * 72];   // L1 output; reused as V (L4 out)
    __shared__ ushort sHIN[64 * 40];  // [SH16 | geo16] (+ pad)
    __shared__ ushort sU[64 * 72];    // L3 output

    const int tid = threadIdx.x;
    const int p0  = blockIdx.x * 64;

    // ---- stage X: enc (level-major packed bf16) -> [point][32] ----
    {
        const int pt = tid & 63;
        const int l0 = (tid >> 6) * 4;
        const int p  = p0 + pt;
#pragma unroll
        for (int l = l0; l < l0 + 4; ++l) {
            *(uint32_t*)&sX[pt * 40 + 2 * l] = enc_ws[l * NPTS + p];
        }
    }

    // ---- stage SH16 into sHIN[:, 0:16] ----
    if (tid < 64) {
        const int p = p0 + tid;
        const int b = p / NS;
        const float* M = c2w + b * 12;
        const float n0 = normals[3 * b + 0];
        const float n1 = normals[3 * b + 1];
        const float n2 = normals[3 * b + 2];
        float x = M[0] * n0 + M[4] * n1 + M[8] * n2;
        float y = M[1] * n0 + M[5] * n1 + M[9] * n2;
        float z = M[2] * n0 + M[6] * n1 + M[10] * n2;
        x = (x + 1.0f) * 0.5f;
        y = (y + 1.0f) * 0.5f;
        z = (z + 1.0f) * 0.5f;
        const float xx = x * x, yy = y * y, zz = z * z;
        float sh[16];
        sh[0]  = 0.28209479177387814f;
        sh[1]  = -0.48860251190291987f * y;
        sh[2]  = 0.48860251190291987f * z;
        sh[3]  = -0.48860251190291987f * x;
        sh[4]  = 1.0925484305920792f * x * y;
        sh[5]  = -1.0925484305920792f * y * z;
        sh[6]  = 0.94617469575756f * zz - 0.31539156525252f;
        sh[7]  = -1.0925484305920792f * x * z;
        sh[8]  = 0.5462742152960396f * (xx - yy);
        sh[9]  = 0.5900435899266435f * y * (3.0f * xx - yy);
        sh[10] = 2.890611442640554f * x * y * z;
        sh[11] = 0.4570457994644657f * y * (5.0f * zz - 1.0f);
        sh[12] = 0.37317633259011546f * z * (5.0f * zz - 3.0f);
        sh[13] = 0.4570457994644657f * x * (5.0f * zz - 1.0f);
        sh[14] = 1.445305721320277f * z * (xx - yy);
        sh[15] = 0.5900435899266435f * x * (xx - 3.0f * yy);
#pragma unroll
        for (int i = 0; i < 16; ++i) sHIN[tid * 40 + i] = f2b(sh[i]);
    }

    const int lane = tid & 63;
    const int wv   = tid >> 6;
    const int l15  = lane & 15;
    const int quad = lane >> 4;
    float b1v[4], hb1v[4], hb2v[4];
#pragma unroll
    for (int nt = 0; nt < 4; ++nt) {
        b1v[nt]  = b1[nt * 16 + l15];
        hb1v[nt] = hb1[nt * 16 + l15];
        hb2v[nt] = hb2[nt * 16 + l15];
    }
    const float b2v  = b2[l15];
    const float hb3v = (l15 < 3) ? hb3[l15] : 0.0f;

    const ushort* fb = bank + lane * 8;  // this lane's slot in each fragment
#define FRAG(f) (*(const short8*)(fb + (f) * 512))

    __syncthreads();

    const int arow  = wv * 16 + l15;
    const int crow0 = wv * 16 + quad * 4;
    const f32x4 zero = {0.0f, 0.0f, 0.0f, 0.0f};

    // ---- L1: X(32) @ W1 -> 64, +b1, relu -> sA1 ----
    {
        const short8 a = *(const short8*)&sX[arow * 40 + quad * 8];
        f32x4 c[4];
#pragma unroll
        for (int nt = 0; nt < 4; ++nt) c[nt] = MFMA16(a, FRAG(nt), zero);
#pragma unroll
        for (int nt = 0; nt < 4; ++nt)
#pragma unroll
            for (int r = 0; r < 4; ++r) {
                const float v = fmaxf(c[nt][r] + b1v[nt], 0.0f);
                sA1[(crow0 + r) * 72 + nt * 16 + l15] = f2b(v);
            }
    }
    __syncthreads();

    // ---- L2: A1(64) @ W2 -> 16 geo, +b2, relu -> sHIN[:,16:32] ----
    {
        const short8 a0 = *(const short8*)&sA1[arow * 72 + quad * 8];
        const short8 a1 = *(const short8*)&sA1[arow * 72 + 32 + quad * 8];
        f32x4 c = MFMA16(a0, FRAG(4), zero);
        c = MFMA16(a1, FRAG(5), c);
#pragma unroll
        for (int r = 0; r < 4; ++r) {
            const float v = fmaxf(c[r] + b2v, 0.0f);
            sHIN[(crow0 + r) * 40 + 16 + l15] = f2b(v);
        }
    }
    __syncthreads();

    // ---- L3: HIN(32) @ H1 -> 64, +hb1, relu -> sU ----
    {
        const short8 a = *(const short8*)&sHIN[arow * 40 + quad * 8];
        f32x4 c[4];
#pragma unroll
        for (int nt = 0; nt < 4; ++nt) c[nt] = MFMA16(a, FRAG(6 + nt), zero);
#pragma unroll
        for (int nt = 0; nt < 4; ++nt)
#pragma unroll
            for (int r = 0; r < 4; ++r) {
                const float v = fmaxf(c[nt][r] + hb1v[nt], 0.0f);
                sU[(crow0 + r) * 72 + nt * 16 + l15] = f2b(v);
            }
    }
    __syncthreads();

    // ---- L4: U(64) @ H2 -> 64, +hb2, relu -> sA1 (reused as V) ----
    {
        const short8 a0 = *(const short8*)&sU[arow * 72 + quad * 8];
        const short8 a1 = *(const short8*)&sU[arow * 72 + 32 + quad * 8];
        f32x4 c[4];
#pragma unroll
        for (int nt = 0; nt < 4; ++nt) {
            f32x4 t = MFMA16(a0, FRAG(10 + nt * 2), zero);
            c[nt] = MFMA16(a1, FRAG(11 + nt * 2), t);
        }
        __syncthreads();   // WAR on sA1 between all waves
#pragma unroll
        for (int nt = 0; nt < 4; ++nt)
#pragma unroll
            for (int r = 0; r < 4; ++r) {
                const float v = fmaxf(c[nt][r] + hb2v[nt], 0.0f);
                sA1[(crow0 + r) * 72 + nt * 16 + l15] = f2b(v);
            }
    }
    __syncthreads();

    // ---- L5: V(64) @ H3 -> 3, +hb3, sigmoid -> rgb ----
    {
        const short8 a0 = *(const short8*)&sA1[arow * 72 + quad * 8];
        const short8 a1 = *(const short8*)&sA1[arow * 72 + 32 + quad * 8];
        f32x4 c = MFMA16(a0, FRAG(18), zero);
        c = MFMA16(a1, FRAG(19), c);
        if (l15 < 3) {
#pragma unroll
            for (int r = 0; r < 4; ++r) {
                rgb_out[3 * (p0 + crow0 + r) + l15] = sigmoidf(c[r] + hb3v);
            }
        }
    }
#undef FRAG
}

// reduce: one 64-thread block per batch. Softmax over S=48, weighted rgb sum.
__global__ __launch_bounds__(64) void reduce_kernel(
    const float* __restrict__ densities,
    const float* __restrict__ rgb,
    float* __restrict__ out)
{
    const int b = blockIdx.x;
    const int t = threadIdx.x;
    const bool valid = t < NS;

    float d = valid ? densities[b * NS + t] : -INFINITY;
    float m = d;
#pragma unroll
    for (int off = 32; off > 0; off >>= 1) m = fmaxf(m, __shfl_xor(m, off));
    float e = valid ? expf(d - m) : 0.0f;
    float sum = e;
#pragma unroll
    for (int off = 32; off > 0; off >>= 1) sum += __shfl_xor(sum, off);
    const float w = e / sum;

    float r0 = 0.0f, r1 = 0.0f, r2 = 0.0f;
    if (valid) {
        const int base = (b * NS + t) * 3;
        r0 = w * rgb[base + 0];
        r1 = w * rgb[base + 1];
        r2 = w * rgb[base + 2];
    }
#pragma unroll
    for (int off = 32; off > 0; off >>= 1) {
        r0 += __shfl_xor(r0, off);
        r1 += __shfl_xor(r1, off);
        r2 += __shfl_xor(r2, off);
    }
    if (t == 0) {
        out[3 * b + 0] = r0;
        out[3 * b + 1] = r1;
        out[3 * b + 2] = r2;
    }
}

extern "C" void kernel_launch(void* const* d_in, const int* in_sizes, int n_in,
                              void* d_out, int out_size, void* d_ws, size_t ws_size,
                              hipStream_t stream) {
    const float* positions = (const float*)d_in[0];
    const float* densities = (const float*)d_in[1];
    const float* normals   = (const float*)d_in[2];
    const float* c2w       = (const float*)d_in[3];
    const float* table     = (const float*)d_in[4];
    const float* w1  = (const float*)d_in[5];
    const float* b1  = (const float*)d_in[6];
    const float* w2  = (const float*)d_in[7];
    const float* b2  = (const float*)d_in[8];
    const float* h1  = (const float*)d_in[9];
    const float* hb1 = (const float*)d_in[10];
    const float* h2  = (const float*)d_in[11];
    const float* hb2 = (const float*)d_in[12];
    const float* h3  = (const float*)d_in[13];
    const float* hb3 = (const float*)d_in[14];
    float* out = (float*)d_out;

    // ws layout: bank (20 KB) | tb16 (32 MB, optional) | enc (12.6 MB) | rgb
    const size_t BANK_B = 20 * 1024;
    const size_t TB16_B = (size_t)NLEV * TSIZE * 4;
    const size_t ENC_B  = (size_t)NLEV * NPTS * 4;
    const size_t RGB_B  = (size_t)NPTS * 3 * 4;
    const bool use_b16 = ws_size >= BANK_B + TB16_B + ENC_B + RGB_B;

    ushort*   bank = (ushort*)d_ws;
    uint32_t* tb16 = use_b16 ? (uint32_t*)((char*)d_ws + BANK_B) : nullptr;
    char*     rest = (char*)d_ws + BANK_B + (use_b16 ? TB16_B : 0);
    uint32_t* enc_ws = (uint32_t*)rest;
    float*    rgb_ws = (float*)(rest + ENC_B);

    Scales sc;
    const double growth = exp((log(2048.0) - log(16.0)) / 15.0);
    for (int i = 0; i < NLEV; ++i)
        sc.s[i] = (float)floor(16.0 * pow(growth, (double)i));

    prep_kernel<<<4096, 256, 0, stream>>>(w1, w2, h1, h2, h3, table, bank, tb16);
    if (use_b16) {
        encode_kernel_b16<<<(NPTS / 256) * NLEV, 256, 0, stream>>>(
            positions, c2w, tb16, enc_ws, sc);
    } else {
        encode_kernel_f32<<<(NPTS / 256) * NLEV, 256, 0, stream>>>(
            positions, c2w, table, enc_ws, sc);
    }
    mfma_mlp_kernel<<<NPTS / 64, 256, 0, stream>>>(
        enc_ws, normals, c2w, bank, b1, b2, hb1, hb2, hb3, rgb_ws);
    reduce_kernel<<<NB, 64, 0, stream>>>(densities, rgb_ws, out);
}

// Round 9
// 218.490 us; speedup vs baseline: 1.2571x; 1.0902x over previous
//
#include <hip/hip_runtime.h>
#include <math.h>
#include <stdint.h>

#define NLEV 16
#define TSIZE (1u << 19)
#define NB 4096
#define NS 48
#define NPTS (NB * NS)

typedef __attribute__((ext_vector_type(8))) short short8;
typedef __attribute__((ext_vector_type(4))) float f32x4;

struct Scales { float s[NLEV]; };

__device__ __forceinline__ uint32_t hash3(uint32_t x, uint32_t y, uint32_t z) {
    return (x ^ (y * 2654435761u) ^ (z * 805459861u)) & (TSIZE - 1u);
}

__device__ __forceinline__ float sigmoidf(float v) {
    return 1.0f / (1.0f + expf(-v));
}

// fp32 -> bf16 (round to nearest even), raw ushort bits
__device__ __forceinline__ ushort f2b(float f) {
    union { float f; uint32_t u; } v; v.f = f;
    uint32_t r = (v.u + 0x7FFFu + ((v.u >> 16) & 1u)) >> 16;
    return (ushort)r;
}

// Compiler fence + LDS drain: makes per-wave LDS write->read chaining sound
// (round-6 race was COMPILER reordering of ds_read before ds_write; HW DS is
// in-order per wave, lgkmcnt(0) drains outstanding DS ops).
#define LDS_FENCE() asm volatile("s_waitcnt lgkmcnt(0)" ::: "memory")

#define MFMA16(a, b, c) __builtin_amdgcn_mfma_f32_16x16x32_bf16((a), (b), (c), 0, 0, 0)

// k1: encode (fp32 table, request-rate-bound at ~16 req/cy/XCD — structural).
// 1-D grid, level = bid & 15 (XCD pinning heuristic). Last block instead
// builds the 20-fragment weight bank (ready before k2 by stream order).
// Fragment bank: 20 B-fragments, 64 lanes x 8 bf16 each, lane-ordered:
//   f0..3 W1^T | f4..5 W2^T | f6..9 H1^T | f10..17 H2^T (nt*2+kk) |
//   f18..19 H3^T (cols>=3 zero)
__global__ __launch_bounds__(256) void encode_kernel(
    const float* __restrict__ positions,
    const float* __restrict__ c2w,
    const float* __restrict__ table,
    const float* __restrict__ w1, const float* __restrict__ w2,
    const float* __restrict__ h1, const float* __restrict__ h2,
    const float* __restrict__ h3,
    uint32_t* __restrict__ enc_ws,
    ushort* __restrict__ bank,
    Scales sc)
{
    const int bid = blockIdx.x;
    if (bid == (NPTS / 256) * NLEV) {
        // ---- bank build (one block; hidden under the gather blocks) ----
        for (int idx = threadIdx.x; idx < 20 * 512; idx += 256) {
            const int f    = idx >> 9;
            const int r    = idx & 511;
            const int lane = r >> 3;
            const int j    = r & 7;
            const int l15  = lane & 15;
            const int quad = lane >> 4;
            const int k8   = quad * 8 + j;
            float val;
            if (f < 4) {
                val = w1[k8 * 64 + f * 16 + l15];
            } else if (f < 6) {
                val = w2[((f - 4) * 32 + k8) * 16 + l15];
            } else if (f < 10) {
                val = h1[k8 * 64 + (f - 6) * 16 + l15];
            } else if (f < 18) {
                const int t = f - 10, nt = t >> 1, kk = t & 1;
                val = h2[(kk * 32 + k8) * 64 + nt * 16 + l15];
            } else {
                val = (l15 < 3) ? h3[((f - 18) * 32 + k8) * 3 + l15] : 0.0f;
            }
            bank[idx] = f2b(val);
        }
        return;
    }

    const int l = bid & 15;                 // wave-uniform level
    const int p = (bid >> 4) * 256 + threadIdx.x;
    const int b = p / NS;

    const float* M = c2w + b * 12;
    const float px = positions[3 * p + 0];
    const float py = positions[3 * p + 1];
    const float pz = positions[3 * p + 2];
    const float dx = px - M[3], dy = py - M[7], dz = pz - M[11];
    float qx = M[0] * dx + M[4] * dy + M[8] * dz;
    float qy = M[1] * dx + M[5] * dy + M[9] * dz;
    float qz = M[2] * dx + M[6] * dy + M[10] * dz;
    qx = (qx + 1.0f) * 0.5f;
    qy = (qy + 1.0f) * 0.5f;
    qz = (qz + 1.0f) * 0.5f;
    const bool sel = (qx > 0.0f) && (qx < 1.0f) &&
                     (qy > 0.0f) && (qy < 1.0f) &&
                     (qz > 0.0f) && (qz < 1.0f);
    if (!sel) { qx = 0.0f; qy = 0.0f; qz = 0.0f; }

    const float s = sc.s[l];
    const float sx = qx * s, sy = qy * s, sz = qz * s;
    const float fx = floorf(sx), fy = floorf(sy), fz = floorf(sz);
    const float cx = ceilf(sx),  cy = ceilf(sy),  cz = ceilf(sz);
    const float ox = sx - fx, oy = sy - fy, oz = sz - fz;
    const uint32_t fxi = (uint32_t)fx, fyi = (uint32_t)fy, fzi = (uint32_t)fz;
    const uint32_t cxi = (uint32_t)cx, cyi = (uint32_t)cy, czi = (uint32_t)cz;

    const float2* tab = (const float2*)table + (uint32_t)l * TSIZE;
    const float2 g0 = tab[hash3(cxi, cyi, czi)];
    const float2 g1 = tab[hash3(cxi, fyi, czi)];
    const float2 g2 = tab[hash3(fxi, fyi, czi)];
    const float2 g3 = tab[hash3(fxi, cyi, czi)];
    const float2 g4 = tab[hash3(cxi, cyi, fzi)];
    const float2 g5 = tab[hash3(cxi, fyi, fzi)];
    const float2 g6 = tab[hash3(fxi, fyi, fzi)];
    const float2 g7 = tab[hash3(fxi, cyi, fzi)];

    const float omx = 1.0f - ox, omy = 1.0f - oy, omz = 1.0f - oz;
    float f03x = g0.x * ox + g3.x * omx, f03y = g0.y * ox + g3.y * omx;
    float f12x = g1.x * ox + g2.x * omx, f12y = g1.y * ox + g2.y * omx;
    float f56x = g5.x * ox + g6.x * omx, f56y = g5.y * ox + g6.y * omx;
    float f47x = g4.x * ox + g7.x * omx, f47y = g4.y * ox + g7.y * omx;
    float ax = f03x * oy + f12x * omy, ay = f03y * oy + f12y * omy;
    float bx = f47x * oy + f56x * omy, by = f47y * oy + f56y * omy;
    const float ex = ax * oz + bx * omz;
    const float ey = ay * oz + by * omz;
    enc_ws[l * NPTS + p] = ((uint32_t)f2b(ey) << 16) | (uint32_t)f2b(ex);
}

// k2: tail — MLP + softmax-reduce. One 64-thread wave per batch (48 points
// = 3 MFMA m-tiles). All LDS dataflow is intra-wave (rows 0..47 private to
// the wave) => no __syncthreads anywhere; LDS_FENCE() between stages pins
// the compiler and drains DS. Buffer aliasing (lifetimes are disjoint):
//   bufA: sX (L1 in)   then sU (L3 out)
//   bufB: sA1 (L1 out) then sV (L4 out)
//   bufC: sHIN [SH16|geo] (dead after L3), then sW (softmax weights)
// MFMA layouts (verified m89/m120): A[m=lane&15][k=quad*8+j],
// B[n=lane&15][k=quad*8+j], C/D col=lane&15, row=quad*4+reg.
__global__ __launch_bounds__(64) void tail_kernel(
    const uint32_t* __restrict__ enc_ws,
    const float* __restrict__ densities,
    const float* __restrict__ normals,
    const float* __restrict__ c2w,
    const ushort* __restrict__ bank,
    const float* __restrict__ b1, const float* __restrict__ b2,
    const float* __restrict__ hb1, const float* __restrict__ hb2,
    const float* __restrict__ hb3,
    float* __restrict__ out)
{
    __shared__ ushort bufA[48 * 72];
    __shared__ ushort bufB[48 * 72];
    __shared__ ushort bufC[48 * 40];

    const int bidb = blockIdx.x;       // batch
    const int p0   = bidb * NS;
    const int lane = threadIdx.x;
    const int l15  = lane & 15;
    const int quad = lane >> 4;

    // ---- stage X: 48 pts x 16 levels from level-major enc_ws -> bufA ----
#pragma unroll
    for (int i = 0; i < 12; ++i) {
        const int flat = i * 64 + lane;       // < 768
        const int l = flat / 48;
        const int j = flat - l * 48;
        *(uint32_t*)&bufA[j * 72 + 2 * l] = enc_ws[l * NPTS + p0 + j];
    }

    // ---- SH16 (identical for the whole batch): each lane keeps sh[l15] ----
    {
        const float* M = c2w + bidb * 12;
        const float n0 = normals[3 * bidb + 0];
        const float n1 = normals[3 * bidb + 1];
        const float n2 = normals[3 * bidb + 2];
        float x = M[0] * n0 + M[4] * n1 + M[8] * n2;
        float y = M[1] * n0 + M[5] * n1 + M[9] * n2;
        float z = M[2] * n0 + M[6] * n1 + M[10] * n2;
        x = (x + 1.0f) * 0.5f;
        y = (y + 1.0f) * 0.5f;
        z = (z + 1.0f) * 0.5f;
        const float xx = x * x, yy = y * y, zz = z * z;
        float v = 0.28209479177387814f;
        v = (l15 == 1)  ? -0.48860251190291987f * y : v;
        v = (l15 == 2)  ?  0.48860251190291987f * z : v;
        v = (l15 == 3)  ? -0.48860251190291987f * x : v;
        v = (l15 == 4)  ?  1.0925484305920792f * x * y : v;
        v = (l15 == 5)  ? -1.0925484305920792f * y * z : v;
        v = (l15 == 6)  ?  0.94617469575756f * zz - 0.31539156525252f : v;
        v = (l15 == 7)  ? -1.0925484305920792f * x * z : v;
        v = (l15 == 8)  ?  0.5462742152960396f * (xx - yy) : v;
        v = (l15 == 9)  ?  0.5900435899266435f * y * (3.0f * xx - yy) : v;
        v = (l15 == 10) ?  2.890611442640554f * x * y * z : v;
        v = (l15 == 11) ?  0.4570457994644657f * y * (5.0f * zz - 1.0f) : v;
        v = (l15 == 12) ?  0.37317633259011546f * z * (5.0f * zz - 3.0f) : v;
        v = (l15 == 13) ?  0.4570457994644657f * x * (5.0f * zz - 1.0f) : v;
        v = (l15 == 14) ?  1.445305721320277f * z * (xx - yy) : v;
        v = (l15 == 15) ?  0.5900435899266435f * x * (xx - 3.0f * yy) : v;
        const ushort shb = f2b(v);
#pragma unroll
        for (int i = 0; i < 12; ++i) {
            bufC[(i * 4 + quad) * 40 + l15] = shb;   // SH cols for all 48 rows
        }
    }

    // ---- per-lane biases ----
    float b1v[4], hb1v[4], hb2v[4];
#pragma unroll
    for (int nt = 0; nt < 4; ++nt) {
        b1v[nt]  = b1[nt * 16 + l15];
        hb1v[nt] = hb1[nt * 16 + l15];
        hb2v[nt] = hb2[nt * 16 + l15];
    }
    const float b2v  = b2[l15];
    const float hb3v = (l15 < 3) ? hb3[l15] : 0.0f;

    const ushort* fb = bank + lane * 8;
#define FRAG(f) (*(const short8*)(fb + (f) * 512))

    const f32x4 zero = {0.0f, 0.0f, 0.0f, 0.0f};
    LDS_FENCE();

    // ---- L1: X(32) @ W1 -> 64, +b1, relu -> bufB ----
    {
        short8 w[4];
#pragma unroll
        for (int nt = 0; nt < 4; ++nt) w[nt] = FRAG(nt);
        f32x4 c[3][4];
#pragma unroll
        for (int t = 0; t < 3; ++t) {
            const short8 a = *(const short8*)&bufA[(16 * t + l15) * 72 + quad * 8];
#pragma unroll
            for (int nt = 0; nt < 4; ++nt) c[t][nt] = MFMA16(a, w[nt], zero);
        }
        LDS_FENCE();
#pragma unroll
        for (int t = 0; t < 3; ++t)
#pragma unroll
            for (int nt = 0; nt < 4; ++nt)
#pragma unroll
                for (int r = 0; r < 4; ++r) {
                    const float v = fmaxf(c[t][nt][r] + b1v[nt], 0.0f);
                    bufB[(16 * t + quad * 4 + r) * 72 + nt * 16 + l15] = f2b(v);
                }
    }
    LDS_FENCE();

    // ---- L2: A1(64) @ W2 -> 16 geo, +b2, relu -> bufC cols 16..31 ----
    {
        const short8 w0 = FRAG(4), w1f = FRAG(5);
#pragma unroll
        for (int t = 0; t < 3; ++t) {
            const short8 a0 = *(const short8*)&bufB[(16 * t + l15) * 72 + quad * 8];
            const short8 a1 = *(const short8*)&bufB[(16 * t + l15) * 72 + 32 + quad * 8];
            f32x4 c = MFMA16(a0, w0, zero);
            c = MFMA16(a1, w1f, c);
#pragma unroll
            for (int r = 0; r < 4; ++r) {
                const float v = fmaxf(c[r] + b2v, 0.0f);
                bufC[(16 * t + quad * 4 + r) * 40 + 16 + l15] = f2b(v);
            }
        }
    }
    LDS_FENCE();

    // ---- L3: HIN(32) @ H1 -> 64, +hb1, relu -> bufA (sU) ----
    {
        short8 w[4];
#pragma unroll
        for (int nt = 0; nt < 4; ++nt) w[nt] = FRAG(6 + nt);
        f32x4 c[3][4];
#pragma unroll
        for (int t = 0; t < 3; ++t) {
            const short8 a = *(const short8*)&bufC[(16 * t + l15) * 40 + quad * 8];
#pragma unroll
            for (int nt = 0; nt < 4; ++nt) c[t][nt] = MFMA16(a, w[nt], zero);
        }
        LDS_FENCE();   // bufA reuse: X-reads (L1) long done for this wave
#pragma unroll
        for (int t = 0; t < 3; ++t)
#pragma unroll
            for (int nt = 0; nt < 4; ++nt)
#pragma unroll
                for (int r = 0; r < 4; ++r) {
                    const float v = fmaxf(c[t][nt][r] + hb1v[nt], 0.0f);
                    bufA[(16 * t + quad * 4 + r) * 72 + nt * 16 + l15] = f2b(v);
                }
    }
    LDS_FENCE();

    // ---- L4: U(64) @ H2 -> 64, +hb2, relu -> bufB (sV) ----
    {
        short8 w[8];
#pragma unroll
        for (int f = 0; f < 8; ++f) w[f] = FRAG(10 + f);
        f32x4 c[3][4];
#pragma unroll
        for (int t = 0; t < 3; ++t) {
            const short8 a0 = *(const short8*)&bufA[(16 * t + l15) * 72 + quad * 8];
            const short8 a1 = *(const short8*)&bufA[(16 * t + l15) * 72 + 32 + quad * 8];
#pragma unroll
            for (int nt = 0; nt < 4; ++nt) {
                f32x4 u = MFMA16(a0, w[nt * 2], zero);
                c[t][nt] = MFMA16(a1, w[nt * 2 + 1], u);
            }
        }
        LDS_FENCE();
#pragma unroll
        for (int t = 0; t < 3; ++t)
#pragma unroll
            for (int nt = 0; nt < 4; ++nt)
#pragma unroll
                for (int r = 0; r < 4; ++r) {
                    const float v = fmaxf(c[t][nt][r] + hb2v[nt], 0.0f);
                    bufB[(16 * t + quad * 4 + r) * 72 + nt * 16 + l15] = f2b(v);
                }
    }
    LDS_FENCE();

    // ---- L5: V(64) @ H3 -> 3 (cols>=3 are zero weights) ----
    f32x4 rgbc[3];
    {
        const short8 w0 = FRAG(18), w1f = FRAG(19);
#pragma unroll
        for (int t = 0; t < 3; ++t) {
            const short8 a0 = *(const short8*)&bufB[(16 * t + l15) * 72 + quad * 8];
            const short8 a1 = *(const short8*)&bufB[(16 * t + l15) * 72 + 32 + quad * 8];
            f32x4 c = MFMA16(a0, w0, zero);
            rgbc[t] = MFMA16(a1, w1f, c);
        }
    }
#undef FRAG

    // ---- softmax over the batch's 48 densities (wave shuffles) ----
    const float d = (lane < NS) ? densities[p0 + lane] : -INFINITY;
    float m = d;
#pragma unroll
    for (int off = 32; off > 0; off >>= 1) m = fmaxf(m, __shfl_xor(m, off));
    const float e = expf(d - m);              // -inf -> 0 for lanes >= 48
    float sum = e;
#pragma unroll
    for (int off = 32; off > 0; off >>= 1) sum += __shfl_xor(sum, off);
    const float wgt = e / sum;

    float* sW = (float*)bufC;                 // bufC dead after L3
    LDS_FENCE();
    if (lane < NS) sW[lane] = wgt;
    LDS_FENCE();

    // ---- weighted sum of sigmoid(rgb): rows held as C-layout frags ----
    float acc = 0.0f;
#pragma unroll
    for (int t = 0; t < 3; ++t)
#pragma unroll
        for (int r = 0; r < 4; ++r) {
            const int row = 16 * t + quad * 4 + r;
            acc += sW[row] * sigmoidf(rgbc[t][r] + hb3v);
        }
    // butterfly over quads (same l15 in lanes {l15, 16+l15, 32+l15, 48+l15})
    acc += __shfl_xor(acc, 16);
    acc += __shfl_xor(acc, 32);
    if (lane < 3) out[bidb * 3 + lane] = acc;
}

extern "C" void kernel_launch(void* const* d_in, const int* in_sizes, int n_in,
                              void* d_out, int out_size, void* d_ws, size_t ws_size,
                              hipStream_t stream) {
    const float* positions = (const float*)d_in[0];
    const float* densities = (const float*)d_in[1];
    const float* normals   = (const float*)d_in[2];
    const float* c2w       = (const float*)d_in[3];
    const float* table     = (const float*)d_in[4];
    const float* w1  = (const float*)d_in[5];
    const float* b1  = (const float*)d_in[6];
    const float* w2  = (const float*)d_in[7];
    const float* b2  = (const float*)d_in[8];
    const float* h1  = (const float*)d_in[9];
    const float* hb1 = (const float*)d_in[10];
    const float* h2  = (const float*)d_in[11];
    const float* hb2 = (const float*)d_in[12];
    const float* h3  = (const float*)d_in[13];
    const float* hb3 = (const float*)d_in[14];
    float* out = (float*)d_out;

    // ws layout: bank (20 KB) | enc (NLEV*NPTS u32 = 12.6 MB)
    ushort*   bank   = (ushort*)d_ws;
    uint32_t* enc_ws = (uint32_t*)((char*)d_ws + 20 * 1024);

    Scales sc;
    const double growth = exp((log(2048.0) - log(16.0)) / 15.0);
    for (int i = 0; i < NLEV; ++i)
        sc.s[i] = (float)floor(16.0 * pow(growth, (double)i));

    const int enc_blocks = (NPTS / 256) * NLEV + 1;   // +1 = bank-build block
    encode_kernel<<<enc_blocks, 256, 0, stream>>>(
        positions, c2w, table, w1, w2, h1, h2, h3, enc_ws, bank, sc);
    tail_kernel<<<NB, 64, 0, stream>>>(
        enc_ws, densities, normals, c2w, bank, b1, b2, hb1, hb2, hb3, out);
}